// Round 8
// baseline (83.952 us; speedup 1.0000x reference)
//
#include <hip/hip_runtime.h>

// ---------------------------------------------------------------------------
// AtomicLinear == x @ W^T + bias.  M=8192, N=2048, K=2048, fp32 in/out.
// R8 = R7 with the 13-bit-offset compile fix (two voffset regs).
// A: LDS 3-buffer ring (96 KB), swizzled image, global_load_lds DMA
// (R4-verified path). B: NO LDS — prepass writes B in per-lane MFMA-fragment
// order; GEMM streams B-frags for tile t+1 from the XCD-pinned L2 panel
// directly into registers (8x global_load_dwordx4, reg-double-buffered).
// Per tile: ONE vmcnt(4) gate (SSA-tied to B regs) + ONE barrier; 8 pipelined
// steps {2 ds_read(mi+2) | 2 bufl/DMA | lgkm(4) tied | 8 MFMA}.
// ---------------------------------------------------------------------------

typedef short          bf16x8  __attribute__((ext_vector_type(8)));
typedef unsigned short ushort8 __attribute__((ext_vector_type(8)));
typedef float          f32x4   __attribute__((ext_vector_type(4)));

static constexpr int Mdim = 8192, Ndim = 2048, Kdim = 2048;
static constexpr int KT4 = 32;                // K-tiles of BK=64
static constexpr int TBA = 256 * 64 * 2;      // 32768 B per A 256x64 tile
static constexpr int TBB = 32768;             // 32768 B per B-frag K-tile image

__device__ __forceinline__ unsigned short f2bf(float f) {
    unsigned u = __float_as_uint(f);
    u += 0x7fffu + ((u >> 16) & 1u);
    return (unsigned short)(u >> 16);
}

// A prepass (verified R4-R6): fp32 row-major -> half-grouped swizzled bf16.
__global__ void convA(const float* __restrict__ src, unsigned short* __restrict__ dst) {
    int g    = blockIdx.x * 256 + threadIdx.x;
    int tile = g >> 11;
    int idx  = g & 2047;
    int h    = idx >> 10;
    int rem  = idx & 1023;
    int p    = rem >> 3, s = rem & 7;
    int c    = s ^ (p & 7);
    int kt   = tile & 31, rt = tile >> 5;
    int r    = (p >> 6) * 128 + h * 64 + (p & 63);

    const float* q = src + (size_t)(rt * 256 + r) * 2048 + kt * 64 + c * 8;
    float4 v0 = *(const float4*)q;
    float4 v1 = *(const float4*)(q + 4);
    ushort8 o;
    o[0] = f2bf(v0.x); o[1] = f2bf(v0.y); o[2] = f2bf(v0.z); o[3] = f2bf(v0.w);
    o[4] = f2bf(v1.x); o[5] = f2bf(v1.y); o[6] = f2bf(v1.z); o[7] = f2bf(v1.w);
    *(ushort8*)(dst + (size_t)g * 8) = o;
}

// B prepass: W [2048][2048] fp32 -> per-lane fragment order.
// Chunk g: l=g&63; kk=(g>>6)&1; ni=(g>>7)&3; wc=(g>>9)&3; kt=(g>>11)&31;
// nt=g>>16.  Element: W[nt*256+wc*64+ni*16+(l&15)][kt*64+kk*32+(l>>4)*8+j].
__global__ void convB(const float* __restrict__ src, unsigned short* __restrict__ dst) {
    int g  = blockIdx.x * 256 + threadIdx.x;
    int l  = g & 63;
    int kk = (g >> 6) & 1;
    int ni = (g >> 7) & 3;
    int wc = (g >> 9) & 3;
    int kt = (g >> 11) & 31;
    int nt = g >> 16;

    int row = nt * 256 + wc * 64 + ni * 16 + (l & 15);
    int col = kt * 64 + kk * 32 + (l >> 4) * 8;
    const float* q = src + (size_t)row * 2048 + col;
    float4 v0 = *(const float4*)q;
    float4 v1 = *(const float4*)(q + 4);
    ushort8 o;
    o[0] = f2bf(v0.x); o[1] = f2bf(v0.y); o[2] = f2bf(v0.z); o[3] = f2bf(v0.w);
    o[4] = f2bf(v1.x); o[5] = f2bf(v1.y); o[6] = f2bf(v1.z); o[7] = f2bf(v1.w);
    *(ushort8*)(dst + (size_t)g * 8) = o;
}

#define GL_LDS16(gsrc, ldst)                                                    \
    __builtin_amdgcn_global_load_lds(                                           \
        (const __attribute__((address_space(1))) void*)(gsrc),                  \
        (__attribute__((address_space(3))) void*)(ldst), 16, 0, 0)

#define DSR(dst, base, OFF)                                                     \
    asm volatile("ds_read_b128 %0, %1 offset:%2" : "=v"(dst) : "v"(base), "i"(OFF))

#define TIE2(N, s)                                                              \
    asm volatile("s_waitcnt lgkmcnt(" #N ")" : "+v"(s[0]), "+v"(s[1]))

#define GATE(N, b)                                                              \
    asm volatile("s_waitcnt vmcnt(" #N ")"                                      \
                 : "+v"(b[0][0]), "+v"(b[0][1]), "+v"(b[1][0]), "+v"(b[1][1]),  \
                   "+v"(b[2][0]), "+v"(b[2][1]), "+v"(b[3][0]), "+v"(b[3][1]))

// 13-bit signed imm: keep OFF <= 3072; VOFF selects voffB (ni 0-1) or
// voffB+4096 (ni 2-3).
#define BUFL(dst, VOFF, OFF)                                                    \
    asm volatile("global_load_dwordx4 %0, %1, %2 offset:%3"                     \
                 : "=v"(dst) : "v"(VOFF), "s"(gBn), "i"(OFF))

#define BAR()   __builtin_amdgcn_s_barrier()
#define PRIO1() __builtin_amdgcn_s_setprio(1)
#define PRIO0() __builtin_amdgcn_s_setprio(0)

template <int MI>
__device__ __forceinline__ void mfma8(f32x4 (&acc)[8][4], bf16x8 (&s)[2],
                                      bf16x8 (&bC)[4][2]) {
#pragma unroll
    for (int ni = 0; ni < 4; ++ni)
#pragma unroll
        for (int kk = 0; kk < 2; ++kk)
            acc[MI][ni] = __builtin_amdgcn_mfma_f32_16x16x32_bf16(
                s[kk], bC[ni][kk], acc[MI][ni], 0, 0, 0);
}

// One K-tile: gate + barrier, then 8 pipelined steps (reads 2 mi ahead).
template <int VM, bool LB, bool DM>
__device__ __forceinline__ void tile7(
    f32x4 (&acc)[8][4], bf16x8 (&bC)[4][2], bf16x8 (&bN)[4][2],
    unsigned aK0, unsigned aK1,
    unsigned long long gBn, unsigned voffB0, unsigned voffB1,
    const char* gAn, char* ldsAn, int tid) {
    bf16x8 s0[2], s1[2], s2[2];
    if constexpr (VM == 4) GATE(4, bC);
    else if constexpr (VM == 0) GATE(0, bC);
    BAR();
    DSR(s0[0], aK0, 0);     DSR(s0[1], aK1, 0);        // mi0
    DSR(s1[0], aK0, 2048);  DSR(s1[1], aK1, 2048);     // mi1
    // step0: +mi2; bufl ni0
    DSR(s2[0], aK0, 4096);  DSR(s2[1], aK1, 4096);
    if constexpr (LB) { BUFL(bN[0][0], voffB0, 0); BUFL(bN[0][1], voffB0, 1024); }
    TIE2(4, s0); PRIO1(); mfma8<0>(acc, s0, bC); PRIO0();
    // step1: +mi3; bufl ni1
    DSR(s0[0], aK0, 6144);  DSR(s0[1], aK1, 6144);
    if constexpr (LB) { BUFL(bN[1][0], voffB0, 2048); BUFL(bN[1][1], voffB0, 3072); }
    TIE2(4, s1); PRIO1(); mfma8<1>(acc, s1, bC); PRIO0();
    // step2: +mi4 (half1); bufl ni2
    DSR(s1[0], aK0, 16384); DSR(s1[1], aK1, 16384);
    if constexpr (LB) { BUFL(bN[2][0], voffB1, 0); BUFL(bN[2][1], voffB1, 1024); }
    TIE2(4, s2); PRIO1(); mfma8<2>(acc, s2, bC); PRIO0();
    // step3: +mi5; bufl ni3
    DSR(s2[0], aK0, 18432); DSR(s2[1], aK1, 18432);
    if constexpr (LB) { BUFL(bN[3][0], voffB1, 2048); BUFL(bN[3][1], voffB1, 3072); }
    TIE2(4, s0); PRIO1(); mfma8<3>(acc, s0, bC); PRIO0();
    // step4: +mi6; DMA A(t+2) halves 0,1
    DSR(s0[0], aK0, 20480); DSR(s0[1], aK1, 20480);
    if constexpr (DM) {
        GL_LDS16(gAn + tid * 16,        ldsAn + tid * 16);
        GL_LDS16(gAn + 8192 + tid * 16, ldsAn + 8192 + tid * 16);
    }
    TIE2(4, s1); PRIO1(); mfma8<4>(acc, s1, bC); PRIO0();
    // step5: +mi7; DMA A(t+2) halves 2,3
    DSR(s1[0], aK0, 22528); DSR(s1[1], aK1, 22528);
    if constexpr (DM) {
        GL_LDS16(gAn + 16384 + tid * 16, ldsAn + 16384 + tid * 16);
        GL_LDS16(gAn + 24576 + tid * 16, ldsAn + 24576 + tid * 16);
    }
    TIE2(4, s2); PRIO1(); mfma8<5>(acc, s2, bC); PRIO0();
    // step6
    TIE2(2, s0); PRIO1(); mfma8<6>(acc, s0, bC); PRIO0();
    // step7 (lgkm fully drained -> ring rotation safe)
    TIE2(0, s1); PRIO1(); mfma8<7>(acc, s1, bC); PRIO0();
}

// 256x256 block tile, 512 threads (8 waves 2M x 4N), wave tile 128x64.
__global__ __launch_bounds__(512, 2) void gemm7(
    const unsigned short* __restrict__ xa, const unsigned short* __restrict__ wbf,
    const float* __restrict__ bias, float* __restrict__ out) {
    extern __shared__ char smem[];               // 3 x 32 KB A-ring

    const int tid  = threadIdx.x;
    const int lane = tid & 63, wid = tid >> 6;
    const int wr   = wid >> 2;                   // 0..1
    const int wc   = wid & 3;                    // 0..3
    const int fr   = lane & 15, fq = lane >> 4;

    const int bid = blockIdx.x;                  // 256 blocks = 1/CU
    const int nt  = bid & 7;                     // XCD-pinned B panel (T1)
    const int mt  = bid >> 3;                    // 0..31

    const char* aT = (const char*)xa + (size_t)mt * KT4 * TBA;
    const char* bP = (const char*)wbf + (size_t)nt * KT4 * TBB;

    const unsigned lds0 = (unsigned)(size_t)smem;
    const int slot0 = fq ^ (fr & 7);
    const int slot1 = (4 + fq) ^ (fr & 7);
    const unsigned aRow = (unsigned)((wr * 64 + fr) * 128);
    const unsigned aK0b0 = lds0 + aRow + slot0 * 16;
    const unsigned aK1b0 = lds0 + aRow + slot1 * 16;
    const unsigned aK0b1 = aK0b0 + 32768u, aK1b1 = aK1b0 + 32768u;
    const unsigned aK0b2 = aK0b0 + 65536u, aK1b2 = aK1b0 + 65536u;
    const unsigned voffB0 = (unsigned)(wc * 8192 + lane * 16);
    const unsigned voffB1 = voffB0 + 4096u;

    f32x4 acc[8][4];
#pragma unroll
    for (int i = 0; i < 8; ++i)
#pragma unroll
        for (int j = 0; j < 4; ++j)
            acc[i][j] = f32x4{0.f, 0.f, 0.f, 0.f};
    bf16x8 bfU[4][2], bfV[4][2];

    // Prologue. Queue order: dmaA(0) x4, buflB(0) x8, dmaA(1) x4.
    GL_LDS16(aT + tid * 16,         smem + tid * 16);
    GL_LDS16(aT + 8192 + tid * 16,  smem + 8192 + tid * 16);
    GL_LDS16(aT + 16384 + tid * 16, smem + 16384 + tid * 16);
    GL_LDS16(aT + 24576 + tid * 16, smem + 24576 + tid * 16);
    {
        unsigned long long gBn = (unsigned long long)bP;
        BUFL(bfU[0][0], voffB0, 0);    BUFL(bfU[0][1], voffB0, 1024);
        BUFL(bfU[1][0], voffB0, 2048); BUFL(bfU[1][1], voffB0, 3072);
        BUFL(bfU[2][0], voffB1, 0);    BUFL(bfU[2][1], voffB1, 1024);
        BUFL(bfU[3][0], voffB1, 2048); BUFL(bfU[3][1], voffB1, 3072);
    }
    GL_LDS16(aT + TBA + tid * 16,         smem + 32768 + tid * 16);
    GL_LDS16(aT + TBA + 8192 + tid * 16,  smem + 40960 + tid * 16);
    GL_LDS16(aT + TBA + 16384 + tid * 16, smem + 49152 + tid * 16);
    GL_LDS16(aT + TBA + 24576 + tid * 16, smem + 57344 + tid * 16);
    // (tile0's own GATE(4) retires dmaA(0)+buflB(0), leaves dmaA(1) in flight)

    // Steady: 5 iters x 6 tiles (t = 6it .. 6it+5), then t30, t31.
#define T7(TT, K0, K1, BC, BN, CB)                                              \
    tile7<4, true, true>(acc, BC, BN, K0, K1,                                   \
        (unsigned long long)(bP + (size_t)((TT) + 1) * TBB), voffB0, voffB1,    \
        aT + (size_t)((TT) + 2) * TBA, smem + (CB) * 32768, tid)

#pragma unroll 1
    for (int it = 0; it < 5; ++it) {
        const int t = 6 * it;
        T7(t + 0, aK0b0, aK1b0, bfU, bfV, 2);
        T7(t + 1, aK0b1, aK1b1, bfV, bfU, 0);
        T7(t + 2, aK0b2, aK1b2, bfU, bfV, 1);
        T7(t + 3, aK0b0, aK1b0, bfV, bfU, 2);
        T7(t + 4, aK0b1, aK1b1, bfU, bfV, 0);
        T7(t + 5, aK0b2, aK1b2, bfV, bfU, 1);
    }
    // t30: buf0, consumes bfU, loads B(31)->bfV, no DMA.
    tile7<4, true, false>(acc, bfU, bfV, aK0b0, aK1b0,
                          (unsigned long long)(bP + (size_t)31 * TBB),
                          voffB0, voffB1, aT, smem, tid);
    // t31: buf1, consumes bfV, nothing to load.
    tile7<0, false, false>(acc, bfV, bfU, aK0b1, aK1b1,
                           (unsigned long long)bP, voffB0, voffB1,
                           aT, smem, tid);
#undef T7

    // Epilogue: row = mt*256 + wr*128 + (mi>>2)*64 + (mi&3)*16 + fq*4 + rr;
    //           col = nt*256 + wc*64 + ni*16 + fr.
    const int gr0 = mt * 256 + wr * 128 + fq * 4;
    const int gc0 = nt * 256 + wc * 64;
#pragma unroll
    for (int ni = 0; ni < 4; ++ni) {
        const int cn = gc0 + ni * 16 + fr;
        const float bv = bias[cn];
#pragma unroll
        for (int mi = 0; mi < 8; ++mi) {
            const int rm = gr0 + (mi >> 2) * 64 + (mi & 3) * 16;
#pragma unroll
            for (int rr = 0; rr < 4; ++rr)
                out[(size_t)(rm + rr) * Ndim + cn] = acc[mi][ni][rr] + bv;
        }
    }
}

// Correct-but-slow fp32 fallback if workspace is too small for bf16 copies.
__global__ void fallback_gemm(const float* __restrict__ x, const float* __restrict__ w,
                              const float* __restrict__ bias, float* __restrict__ out) {
    __shared__ float As[64][17];
    __shared__ float Bs[64][17];
    int tx = threadIdx.x & 15, ty = threadIdx.x >> 4;
    int m0 = blockIdx.y * 64, n0 = blockIdx.x * 64;
    float acc[4][4] = {};
    for (int k0 = 0; k0 < Kdim; k0 += 16) {
#pragma unroll
        for (int i = 0; i < 4; ++i) {
            int idx = threadIdx.x + i * 256;
            int rr = idx >> 4, cc = idx & 15;
            As[rr][cc] = x[(size_t)(m0 + rr) * Kdim + k0 + cc];
            Bs[rr][cc] = w[(size_t)(n0 + rr) * Kdim + k0 + cc];
        }
        __syncthreads();
#pragma unroll
        for (int kk = 0; kk < 16; ++kk) {
            float a[4], b[4];
#pragma unroll
            for (int i = 0; i < 4; ++i) a[i] = As[ty * 4 + i][kk];
#pragma unroll
            for (int j = 0; j < 4; ++j) b[j] = Bs[tx * 4 + j][kk];
#pragma unroll
            for (int i = 0; i < 4; ++i)
#pragma unroll
                for (int j = 0; j < 4; ++j) acc[i][j] += a[i] * b[j];
        }
        __syncthreads();
    }
#pragma unroll
    for (int i = 0; i < 4; ++i)
#pragma unroll
        for (int j = 0; j < 4; ++j) {
            int gm = m0 + ty * 4 + i, gn = n0 + tx * 4 + j;
            out[(size_t)gm * Ndim + gn] = acc[i][j] + bias[gn];
        }
}

extern "C" void kernel_launch(void* const* d_in, const int* in_sizes, int n_in,
                              void* d_out, int out_size, void* d_ws, size_t ws_size,
                              hipStream_t stream) {
    const float* x    = (const float*)d_in[0];
    const float* w    = (const float*)d_in[1];
    const float* bias = (const float*)d_in[2];
    float* out        = (float*)d_out;

    const size_t needA = (size_t)Mdim * Kdim * sizeof(unsigned short);
    const size_t needB = (size_t)Ndim * Kdim * sizeof(unsigned short);

    if (ws_size >= needA + needB) {
        unsigned short* xa  = (unsigned short*)d_ws;
        unsigned short* wbf = xa + (size_t)Mdim * Kdim;
        convA<<<(Mdim * Kdim / 8) / 256, 256, 0, stream>>>(x, xa);
        convB<<<(Ndim * Kdim / 8) / 256, 256, 0, stream>>>(w, wbf);

        (void)hipFuncSetAttribute((const void*)gemm7,
                                  hipFuncAttributeMaxDynamicSharedMemorySize,
                                  98304);
        gemm7<<<(Mdim / 256) * (Ndim / 256), 512, 98304, stream>>>(
            xa, wbf, bias, out);
    } else {
        dim3 grid(Ndim / 64, Mdim / 64);
        fallback_gemm<<<grid, 256, 0, stream>>>(x, w, bias, out);
    }
}

// Round 9
// 64.377 us; speedup vs baseline: 1.3041x; 1.3041x over previous
//
#include <hip/hip_runtime.h>

// ---------------------------------------------------------------------------
// AtomicLinear == x @ W^T + bias.  M=8192, N=2048, K=2048, fp32 in/out.
// R9: int8 port of R8.  Per-row symmetric quantization (s=rowmax/127) in a
// fused max+quantize prepass; GEMM uses v_mfma_i32_16x16x64_i8 (~1.9x bf16
// rate, 16B/lane frags identical to bf16 path) with K-tiles of 128 elems ->
// only 16 K-tiles.  A: LDS ring-3 (96 KB), swizzled image via global_load_lds.
// B: no LDS - fragment-ordered stream from XCD-pinned L2 panel into regs.
// Epilogue: out = i32acc * s_x[row] * s_w[col] + bias[col]  (fp32, exact bias).
// ---------------------------------------------------------------------------

typedef int            i32x4   __attribute__((ext_vector_type(4)));
typedef float          f32x4   __attribute__((ext_vector_type(4)));

static constexpr int Mdim = 8192, Ndim = 2048, Kdim = 2048;
static constexpr int KT9 = 16;                // K-tiles of 128 elems
static constexpr int TBA = 32768;             // 256 rows x 128 i8 per A tile
static constexpr int TBB = 32768;             // B-frag bytes per K-tile

// ---------------------------------------------------------------------------
// Prepass A: one block per x-row.  Row (2048 f32) -> regs -> rowmax -> i8,
// written into the swizzled tile image (identical byte layout to R8's A):
// tile (rt,kt) 32 KB; halves h at r%128<64... r=(p>>6)*128+h*64+(p&63);
// prow p: 8 slots of 16B, slot = chunk ^ (p&7), chunk = (k%128)/16.
// ---------------------------------------------------------------------------
__global__ void quantA(const float* __restrict__ src, signed char* __restrict__ dst,
                       float* __restrict__ scale) {
    const int row = blockIdx.x;
    const int j   = threadIdx.x;              // 0..255, elems k0 = j*8
    const int lane = j & 63, wid = j >> 6;
    const float* p = src + (size_t)row * 2048 + j * 8;
    float4 v0 = *(const float4*)p;
    float4 v1 = *(const float4*)(p + 4);
    float m = fmaxf(fmaxf(fmaxf(fabsf(v0.x), fabsf(v0.y)), fmaxf(fabsf(v0.z), fabsf(v0.w))),
                    fmaxf(fmaxf(fabsf(v1.x), fabsf(v1.y)), fmaxf(fabsf(v1.z), fabsf(v1.w))));
#pragma unroll
    for (int i = 1; i < 64; i <<= 1) m = fmaxf(m, __shfl_xor(m, i));
    __shared__ float wm[4];
    if (lane == 0) wm[wid] = m;
    __syncthreads();
    const float rm = fmaxf(fmaxf(wm[0], wm[1]), fmaxf(wm[2], wm[3]));
    const float qs = rm > 1e-30f ? 127.0f / rm : 0.0f;
    if (j == 0) scale[row] = rm > 1e-30f ? rm * (1.0f / 127.0f) : 0.0f;

    int q[8];
    q[0] = __float2int_rn(v0.x * qs); q[1] = __float2int_rn(v0.y * qs);
    q[2] = __float2int_rn(v0.z * qs); q[3] = __float2int_rn(v0.w * qs);
    q[4] = __float2int_rn(v1.x * qs); q[5] = __float2int_rn(v1.y * qs);
    q[6] = __float2int_rn(v1.z * qs); q[7] = __float2int_rn(v1.w * qs);
    uint2 pk;
    pk.x = (q[0] & 255) | ((q[1] & 255) << 8) | ((q[2] & 255) << 16) | ((unsigned)(q[3] & 255) << 24);
    pk.y = (q[4] & 255) | ((q[5] & 255) << 8) | ((q[6] & 255) << 16) | ((unsigned)(q[7] & 255) << 24);

    const int rt = row >> 8, r = row & 255;
    const int kt = j >> 4;
    const int c  = (j & 15) >> 1;             // 16-elem chunk within tile
    const int b8 = (j & 1) * 8;
    const int h  = (r >> 6) & 1, pp = (r >> 7) * 64 + (r & 63);
    size_t byte = ((size_t)(rt * 16 + kt)) * TBA + h * 16384 + pp * 128 +
                  (((unsigned)(c ^ (pp & 7))) << 4) + b8;
    *(uint2*)(dst + byte) = pk;
}

// ---------------------------------------------------------------------------
// Prepass B: one block per w-row -> i8 in per-lane fragment order.
// Chunk g = ((((nt*16+kt)*4+wc)*4+ni)*2+kk)*64 + lane, lane = fq*16+fr;
// holds W[nt*256+wc*64+ni*16+fr][kt*128+kk*64+fq*16 .. +15].
// ---------------------------------------------------------------------------
__global__ void quantB(const float* __restrict__ src, signed char* __restrict__ dst,
                       float* __restrict__ scale) {
    const int row = blockIdx.x;
    const int j   = threadIdx.x;
    const int lane = j & 63, wid = j >> 6;
    const float* p = src + (size_t)row * 2048 + j * 8;
    float4 v0 = *(const float4*)p;
    float4 v1 = *(const float4*)(p + 4);
    float m = fmaxf(fmaxf(fmaxf(fabsf(v0.x), fabsf(v0.y)), fmaxf(fabsf(v0.z), fabsf(v0.w))),
                    fmaxf(fmaxf(fabsf(v1.x), fabsf(v1.y)), fmaxf(fabsf(v1.z), fabsf(v1.w))));
#pragma unroll
    for (int i = 1; i < 64; i <<= 1) m = fmaxf(m, __shfl_xor(m, i));
    __shared__ float wm[4];
    if (lane == 0) wm[wid] = m;
    __syncthreads();
    const float rm = fmaxf(fmaxf(wm[0], wm[1]), fmaxf(wm[2], wm[3]));
    const float qs = rm > 1e-30f ? 127.0f / rm : 0.0f;
    if (j == 0) scale[row] = rm > 1e-30f ? rm * (1.0f / 127.0f) : 0.0f;

    int q[8];
    q[0] = __float2int_rn(v0.x * qs); q[1] = __float2int_rn(v0.y * qs);
    q[2] = __float2int_rn(v0.z * qs); q[3] = __float2int_rn(v0.w * qs);
    q[4] = __float2int_rn(v1.x * qs); q[5] = __float2int_rn(v1.y * qs);
    q[6] = __float2int_rn(v1.z * qs); q[7] = __float2int_rn(v1.w * qs);
    uint2 pk;
    pk.x = (q[0] & 255) | ((q[1] & 255) << 8) | ((q[2] & 255) << 16) | ((unsigned)(q[3] & 255) << 24);
    pk.y = (q[4] & 255) | ((q[5] & 255) << 8) | ((q[6] & 255) << 16) | ((unsigned)(q[7] & 255) << 24);

    const int nt = row >> 8, wc = (row >> 6) & 3, ni = (row >> 4) & 3, fr = row & 15;
    const int kt = j >> 4;
    const int kk = (j >> 3) & 1;
    const int fq = (j >> 1) & 3;
    const int b8 = (j & 1) * 8;
    size_t g = ((((size_t)(nt * 16 + kt) * 4 + wc) * 4 + ni) * 2 + kk) * 64 + fq * 16 + fr;
    *(uint2*)(dst + g * 16 + b8) = pk;
}

#define GL_LDS16(gsrc, ldst)                                                    \
    __builtin_amdgcn_global_load_lds(                                           \
        (const __attribute__((address_space(1))) void*)(gsrc),                  \
        (__attribute__((address_space(3))) void*)(ldst), 16, 0, 0)

#define DSR(dst, base, OFF)                                                     \
    asm volatile("ds_read_b128 %0, %1 offset:%2" : "=v"(dst) : "v"(base), "i"(OFF))

#define TIE2(N, s)                                                              \
    asm volatile("s_waitcnt lgkmcnt(" #N ")" : "+v"(s[0]), "+v"(s[1]))

#define GATE(N, b)                                                              \
    asm volatile("s_waitcnt vmcnt(" #N ")"                                      \
                 : "+v"(b[0][0]), "+v"(b[0][1]), "+v"(b[1][0]), "+v"(b[1][1]),  \
                   "+v"(b[2][0]), "+v"(b[2][1]), "+v"(b[3][0]), "+v"(b[3][1]))

#define BUFL(dst, VOFF, OFF)                                                    \
    asm volatile("global_load_dwordx4 %0, %1, %2 offset:%3"                     \
                 : "=v"(dst) : "v"(VOFF), "s"(gBn), "i"(OFF))

#define BAR()   __builtin_amdgcn_s_barrier()
#define PRIO1() __builtin_amdgcn_s_setprio(1)
#define PRIO0() __builtin_amdgcn_s_setprio(0)

template <int MI>
__device__ __forceinline__ void mfma8(i32x4 (&acc)[8][4], i32x4 (&s)[2],
                                      i32x4 (&bC)[4][2]) {
#pragma unroll
    for (int kk = 0; kk < 2; ++kk)
#pragma unroll
        for (int ni = 0; ni < 4; ++ni)
            asm volatile("v_mfma_i32_16x16x64_i8 %0, %1, %2, %0"
                         : "+a"(acc[MI][ni]) : "v"(s[kk]), "v"(bC[ni][kk]));
}

// One K-tile (K=128): gate + barrier, 8 pipelined mi-steps (reads 2 mi ahead).
template <int VM, bool LB, bool DM>
__device__ __forceinline__ void tile9(
    i32x4 (&acc)[8][4], i32x4 (&bC)[4][2], i32x4 (&bN)[4][2],
    unsigned aK0, unsigned aK1,
    unsigned long long gBn, unsigned voffB0, unsigned voffB1,
    const char* gAn, char* ldsAn, int tid) {
    i32x4 s0[2], s1[2], s2[2];
    if constexpr (VM == 4) GATE(4, bC);
    else if constexpr (VM == 0) GATE(0, bC);
    BAR();
    DSR(s0[0], aK0, 0);     DSR(s0[1], aK1, 0);        // mi0
    DSR(s1[0], aK0, 2048);  DSR(s1[1], aK1, 2048);     // mi1
    // step0: +mi2; bufl ni0
    DSR(s2[0], aK0, 4096);  DSR(s2[1], aK1, 4096);
    if constexpr (LB) { BUFL(bN[0][0], voffB0, 0); BUFL(bN[0][1], voffB0, 1024); }
    TIE2(4, s0); PRIO1(); mfma8<0>(acc, s0, bC); PRIO0();
    // step1: +mi3; bufl ni1
    DSR(s0[0], aK0, 6144);  DSR(s0[1], aK1, 6144);
    if constexpr (LB) { BUFL(bN[1][0], voffB0, 2048); BUFL(bN[1][1], voffB0, 3072); }
    TIE2(4, s1); PRIO1(); mfma8<1>(acc, s1, bC); PRIO0();
    // step2: +mi4 (half1); bufl ni2
    DSR(s1[0], aK0, 16384); DSR(s1[1], aK1, 16384);
    if constexpr (LB) { BUFL(bN[2][0], voffB1, 0); BUFL(bN[2][1], voffB1, 1024); }
    TIE2(4, s2); PRIO1(); mfma8<2>(acc, s2, bC); PRIO0();
    // step3: +mi5; bufl ni3
    DSR(s2[0], aK0, 18432); DSR(s2[1], aK1, 18432);
    if constexpr (LB) { BUFL(bN[3][0], voffB1, 2048); BUFL(bN[3][1], voffB1, 3072); }
    TIE2(4, s0); PRIO1(); mfma8<3>(acc, s0, bC); PRIO0();
    // step4: +mi6; DMA A(t+2) halves 0,1
    DSR(s0[0], aK0, 20480); DSR(s0[1], aK1, 20480);
    if constexpr (DM) {
        GL_LDS16(gAn + tid * 16,        ldsAn + tid * 16);
        GL_LDS16(gAn + 8192 + tid * 16, ldsAn + 8192 + tid * 16);
    }
    TIE2(4, s1); PRIO1(); mfma8<4>(acc, s1, bC); PRIO0();
    // step5: +mi7; DMA A(t+2) halves 2,3
    DSR(s1[0], aK0, 22528); DSR(s1[1], aK1, 22528);
    if constexpr (DM) {
        GL_LDS16(gAn + 16384 + tid * 16, ldsAn + 16384 + tid * 16);
        GL_LDS16(gAn + 24576 + tid * 16, ldsAn + 24576 + tid * 16);
    }
    TIE2(4, s2); PRIO1(); mfma8<5>(acc, s2, bC); PRIO0();
    // step6
    TIE2(2, s0); PRIO1(); mfma8<6>(acc, s0, bC); PRIO0();
    // step7 (lgkm fully drained -> ring rotation safe)
    TIE2(0, s1); PRIO1(); mfma8<7>(acc, s1, bC); PRIO0();
}

// 256x256 block tile, 512 threads (8 waves 2M x 4N), wave tile 128x64.
__global__ __launch_bounds__(512, 2) void gemm9(
    const signed char* __restrict__ xa, const signed char* __restrict__ wbf,
    const float* __restrict__ sx, const float* __restrict__ tw,
    const float* __restrict__ bias, float* __restrict__ out) {
    extern __shared__ char smem[];               // 3 x 32 KB A-ring

    const int tid  = threadIdx.x;
    const int lane = tid & 63, wid = tid >> 6;
    const int wr   = wid >> 2;                   // 0..1
    const int wc   = wid & 3;                    // 0..3
    const int fr   = lane & 15, fq = lane >> 4;

    const int bid = blockIdx.x;                  // 256 blocks = 1/CU
    const int nt  = bid & 7;                     // XCD-pinned B panel (T1)
    const int mt  = bid >> 3;                    // 0..31

    const char* aT = (const char*)xa + (size_t)mt * KT9 * TBA;
    const char* bP = (const char*)wbf + (size_t)nt * KT9 * TBB;

    const unsigned lds0 = (unsigned)(size_t)smem;
    const int slot0 = fq ^ (fr & 7);
    const int slot1 = (4 + fq) ^ (fr & 7);
    const unsigned aRow = (unsigned)((wr * 64 + fr) * 128);
    const unsigned aK0b0 = lds0 + aRow + slot0 * 16;
    const unsigned aK1b0 = lds0 + aRow + slot1 * 16;
    const unsigned aK0b1 = aK0b0 + 32768u, aK1b1 = aK1b0 + 32768u;
    const unsigned aK0b2 = aK0b0 + 65536u, aK1b2 = aK1b0 + 65536u;
    const unsigned voffB0 = (unsigned)(wc * 8192 + lane * 16);
    const unsigned voffB1 = voffB0 + 4096u;

    i32x4 acc[8][4];
#pragma unroll
    for (int i = 0; i < 8; ++i)
#pragma unroll
        for (int j = 0; j < 4; ++j)
            acc[i][j] = i32x4{0, 0, 0, 0};
    i32x4 bfU[4][2], bfV[4][2];

    // Prologue. Queue order: dmaA(0) x4, buflB(0) x8, dmaA(1) x4.
    GL_LDS16(aT + tid * 16,         smem + tid * 16);
    GL_LDS16(aT + 8192 + tid * 16,  smem + 8192 + tid * 16);
    GL_LDS16(aT + 16384 + tid * 16, smem + 16384 + tid * 16);
    GL_LDS16(aT + 24576 + tid * 16, smem + 24576 + tid * 16);
    {
        unsigned long long gBn = (unsigned long long)bP;
        BUFL(bfU[0][0], voffB0, 0);    BUFL(bfU[0][1], voffB0, 1024);
        BUFL(bfU[1][0], voffB0, 2048); BUFL(bfU[1][1], voffB0, 3072);
        BUFL(bfU[2][0], voffB1, 0);    BUFL(bfU[2][1], voffB1, 1024);
        BUFL(bfU[3][0], voffB1, 2048); BUFL(bfU[3][1], voffB1, 3072);
    }
    GL_LDS16(aT + TBA + tid * 16,         smem + 32768 + tid * 16);
    GL_LDS16(aT + TBA + 8192 + tid * 16,  smem + 40960 + tid * 16);
    GL_LDS16(aT + TBA + 16384 + tid * 16, smem + 49152 + tid * 16);
    GL_LDS16(aT + TBA + 24576 + tid * 16, smem + 57344 + tid * 16);
    // (tile0's GATE(4) retires dmaA(0)+buflB(0), leaves dmaA(1) in flight)

#define T9(TT, K0, K1, BC, BN, CB)                                              \
    tile9<4, true, true>(acc, BC, BN, K0, K1,                                   \
        (unsigned long long)(bP + (size_t)((TT) + 1) * TBB), voffB0, voffB1,    \
        aT + (size_t)((TT) + 2) * TBA, smem + (CB) * 32768, tid)

    // Steady: 2 iters x 6 tiles (t = 0..11), then t12, t13, t14, t15.
#pragma unroll 1
    for (int it = 0; it < 2; ++it) {
        const int t = 6 * it;
        T9(t + 0, aK0b0, aK1b0, bfU, bfV, 2);
        T9(t + 1, aK0b1, aK1b1, bfV, bfU, 0);
        T9(t + 2, aK0b2, aK1b2, bfU, bfV, 1);
        T9(t + 3, aK0b0, aK1b0, bfV, bfU, 2);
        T9(t + 4, aK0b1, aK1b1, bfU, bfV, 0);
        T9(t + 5, aK0b2, aK1b2, bfV, bfU, 1);
    }
    T9(12, aK0b0, aK1b0, bfU, bfV, 2);           // LB B13, DMA A14 -> buf2
    T9(13, aK0b1, aK1b1, bfV, bfU, 0);           // LB B14, DMA A15 -> buf0
    // t14: buf2, consumes bfU, loads B(15)->bfV, no DMA.
    tile9<4, true, false>(acc, bfU, bfV, aK0b2, aK1b2,
                          (unsigned long long)(bP + (size_t)15 * TBB),
                          voffB0, voffB1, aT, smem, tid);
    // t15: buf0, consumes bfV, nothing to load.
    tile9<0, false, false>(acc, bfV, bfU, aK0b0, aK1b0,
                           (unsigned long long)bP, voffB0, voffB1,
                           aT, smem, tid);
#undef T9

    // Epilogue: row = mt*256 + wr*128 + (mi>>2)*64 + (mi&3)*16 + fq*4 + rr;
    //           col = nt*256 + wc*64 + ni*16 + fr.
    // out = i32 * s_x[row] * s_w[col] + bias[col].
    const int gr0 = mt * 256 + wr * 128 + fq * 4;
    const int gc0 = nt * 256 + wc * 64;
#pragma unroll
    for (int ni = 0; ni < 4; ++ni) {
        const int cn = gc0 + ni * 16 + fr;
        const float tv = tw[cn];
        const float bv = bias[cn];
#pragma unroll
        for (int mi = 0; mi < 8; ++mi) {
            const int rm = gr0 + (mi >> 2) * 64 + (mi & 3) * 16;
            const float4 sv = *(const float4*)&sx[rm];
            out[(size_t)(rm + 0) * Ndim + cn] = (float)acc[mi][ni][0] * sv.x * tv + bv;
            out[(size_t)(rm + 1) * Ndim + cn] = (float)acc[mi][ni][1] * sv.y * tv + bv;
            out[(size_t)(rm + 2) * Ndim + cn] = (float)acc[mi][ni][2] * sv.z * tv + bv;
            out[(size_t)(rm + 3) * Ndim + cn] = (float)acc[mi][ni][3] * sv.w * tv + bv;
        }
    }
}

// Correct-but-slow fp32 fallback if workspace is too small.
__global__ void fallback_gemm(const float* __restrict__ x, const float* __restrict__ w,
                              const float* __restrict__ bias, float* __restrict__ out) {
    __shared__ float As[64][17];
    __shared__ float Bs[64][17];
    int tx = threadIdx.x & 15, ty = threadIdx.x >> 4;
    int m0 = blockIdx.y * 64, n0 = blockIdx.x * 64;
    float acc[4][4] = {};
    for (int k0 = 0; k0 < Kdim; k0 += 16) {
#pragma unroll
        for (int i = 0; i < 4; ++i) {
            int idx = threadIdx.x + i * 256;
            int rr = idx >> 4, cc = idx & 15;
            As[rr][cc] = x[(size_t)(m0 + rr) * Kdim + k0 + cc];
            Bs[rr][cc] = w[(size_t)(n0 + rr) * Kdim + k0 + cc];
        }
        __syncthreads();
#pragma unroll
        for (int kk = 0; kk < 16; ++kk) {
            float a[4], b[4];
#pragma unroll
            for (int i = 0; i < 4; ++i) a[i] = As[ty * 4 + i][kk];
#pragma unroll
            for (int j = 0; j < 4; ++j) b[j] = Bs[tx * 4 + j][kk];
#pragma unroll
            for (int i = 0; i < 4; ++i)
#pragma unroll
                for (int j = 0; j < 4; ++j) acc[i][j] += a[i] * b[j];
        }
        __syncthreads();
    }
#pragma unroll
    for (int i = 0; i < 4; ++i)
#pragma unroll
        for (int j = 0; j < 4; ++j) {
            int gm = m0 + ty * 4 + i, gn = n0 + tx * 4 + j;
            out[(size_t)gm * Ndim + gn] = acc[i][j] + bias[gn];
        }
}

extern "C" void kernel_launch(void* const* d_in, const int* in_sizes, int n_in,
                              void* d_out, int out_size, void* d_ws, size_t ws_size,
                              hipStream_t stream) {
    const float* x    = (const float*)d_in[0];
    const float* w    = (const float*)d_in[1];
    const float* bias = (const float*)d_in[2];
    float* out        = (float*)d_out;

    const size_t needA = (size_t)Mdim * Kdim;            // 16.8 MB i8 image
    const size_t needB = (size_t)Ndim * Kdim;            //  4.2 MB i8 image
    const size_t needS = (Mdim + Ndim) * sizeof(float);  // scales

    if (ws_size >= needA + needB + needS) {
        signed char* xa  = (signed char*)d_ws;
        signed char* wbf = xa + needA;
        float* sx        = (float*)(wbf + needB);
        float* tw        = sx + Mdim;
        quantA<<<Mdim, 256, 0, stream>>>(x, xa, sx);
        quantB<<<Ndim, 256, 0, stream>>>(w, wbf, tw);

        (void)hipFuncSetAttribute((const void*)gemm9,
                                  hipFuncAttributeMaxDynamicSharedMemorySize,
                                  98304);
        gemm9<<<(Mdim / 256) * (Ndim / 256), 512, 98304, stream>>>(
            xa, wbf, sx, tw, bias, out);
    } else {
        dim3 grid(Ndim / 64, Mdim / 64);
        fallback_gemm<<<grid, 256, 0, stream>>>(x, w, bias, out);
    }
}